// Round 21
// baseline (590.667 us; speedup 1.0000x reference)
//
#include <hip/hip_runtime.h>
#include <stdint.h>

typedef __bf16 bf16;
typedef __bf16 bf16x4 __attribute__((ext_vector_type(4)));
typedef __bf16 bf16x8 __attribute__((ext_vector_type(8)));
typedef float f32x4 __attribute__((ext_vector_type(4)));

#define MFMA16(a, b, c) __builtin_amdgcn_mfma_f32_16x16x32_bf16((a), (b), (c), 0, 0, 0)

static constexpr int NB = 4;      // batch
static constexpr int NH = 16;     // heads
static constexpr int SL = 2048;   // seq len
static constexpr int HD = 64;     // head dim
static constexpr int ED = 1024;   // embed
static constexpr int MR = NB * SL; // 8192 rows

__device__ __forceinline__ void gl_lds16(const void* g, void* l) {
    __builtin_amdgcn_global_load_lds(
        (const __attribute__((address_space(1))) unsigned int*)g,
        (__attribute__((address_space(3))) unsigned int*)l, 16, 0, 0);
}

// ------------------- f32 -> bf16 hi/lo split -------------------
__global__ void k_split(const float* __restrict__ src, bf16* __restrict__ hi,
                        bf16* __restrict__ lo, int n4) {
    int i = blockIdx.x * blockDim.x + threadIdx.x;
    if (i >= n4) return;
    const float4 v = ((const float4*)src)[i];
    float vv[4] = {v.x, v.y, v.z, v.w};
    bf16x4 hv, lv;
#pragma unroll
    for (int e = 0; e < 4; ++e) {
        bf16 h = (bf16)vv[e];
        hv[e] = h;
        lv[e] = (bf16)(vv[e] - (float)h);
    }
    ((bf16x4*)hi)[i] = hv;
    ((bf16x4*)lo)[i] = lv;
}

// ------------------- f32 -> bf16 plain cast -------------------
__global__ void k_cast(const float* __restrict__ src, bf16* __restrict__ dst, int n4) {
    int i = blockIdx.x * blockDim.x + threadIdx.x;
    if (i >= n4) return;
    const float4 v = ((const float4*)src)[i];
    bf16x4 hv = {(bf16)v.x, (bf16)v.y, (bf16)v.z, (bf16)v.w};
    ((bf16x4*)dst)[i] = hv;
}

// ------------------- V transpose: [n,h,key,d] -> [n,h,d,key] -------------------
__global__ __launch_bounds__(256) void k_vt(const bf16* __restrict__ v,
                                            bf16* __restrict__ vt) {
    __shared__ bf16 T[256 * 72];   // [key_local][d] padded (+8)
    const int n = blockIdx.z, h = blockIdx.y, kc = blockIdx.x * 256;
    const int tid = threadIdx.x;
    const size_t base1 = ((size_t)n * NH + h) * SL * HD;
    const size_t base2 = ((size_t)n * NH + h) * HD * SL;

#pragma unroll
    for (int ri = 0; ri < 8; ++ri) {
        const int kl = ri * 32 + (tid >> 3), d0 = (tid & 7) * 8;
        const bf16x8 x = *(const bf16x8*)(v + base1 + (size_t)(kc + kl) * HD + d0);
        *(bf16x8*)&T[kl * 72 + d0] = x;
    }
    __syncthreads();

    const int d = tid >> 2, kch = (tid & 3) * 64;
#pragma unroll
    for (int i = 0; i < 8; ++i) {
        bf16x8 y;
#pragma unroll
        for (int e = 0; e < 8; ++e)
            y[e] = T[(kch + i * 8 + e) * 72 + d];
        *(bf16x8*)(vt + base2 + (size_t)d * SL + kc + kch + i * 8) = y;
    }
}

// ------------------- QKV projection GEMM v2: hi-only (1 MFMA/pair) -------------------
__global__ __launch_bounds__(256) void k_qkv_gemm(
    const bf16* __restrict__ xh, const bf16* __restrict__ wh,
    const float* __restrict__ bq, const float* __restrict__ bk,
    const float* __restrict__ bv,
    bf16* __restrict__ qh, bf16* __restrict__ kh, bf16* __restrict__ vh)
{
    __shared__ __attribute__((aligned(16))) bf16 As[128 * 32];
    __shared__ __attribute__((aligned(16))) bf16 Bs[128 * 32];

    const int z  = blockIdx.z;           // 0=q,1=k,2=v
    const int m0 = blockIdx.x * 128;
    const int n0 = blockIdx.y * 128;
    const int tid = threadIdx.x, wave = tid >> 6, lane = tid & 63;
    const int wr = wave >> 1, wc = wave & 1;
    const int fr = lane & 15, fq = lane >> 4;
    const bf16* Wh = wh + (size_t)z * ED * ED;

    const f32x4 z4 = {0.f, 0.f, 0.f, 0.f};
    f32x4 acc[4][4];
#pragma unroll
    for (int i = 0; i < 4; ++i)
#pragma unroll
        for (int j = 0; j < 4; ++j) acc[i][j] = z4;

#pragma unroll 1
    for (int kk = 0; kk < ED; kk += 32) {
#pragma unroll
        for (int r = 0; r < 2; ++r) {
            const int chunk = r * 256 + tid;
            const int row = chunk >> 2, c8 = (chunk & 3) * 8;
            const size_t ax = (size_t)(m0 + row) * ED + kk + c8;
            const size_t bx = (size_t)(n0 + row) * ED + kk + c8;
            const int db = (r * 256 + wave * 64) * 8;   // wave-uniform LDS base
            gl_lds16(xh + ax, &As[db]);
            gl_lds16(Wh + bx, &Bs[db]);
        }
        __syncthreads();
        bf16x8 af[4], bfg[4];
#pragma unroll
        for (int i = 0; i < 4; ++i) {
            const int arow = wr * 64 + i * 16 + fr;
            af[i] = *(const bf16x8*)&As[arow * 32 + fq * 8];
            const int brow = wc * 64 + i * 16 + fr;
            bfg[i] = *(const bf16x8*)&Bs[brow * 32 + fq * 8];
        }
#pragma unroll
        for (int mi = 0; mi < 4; ++mi)
#pragma unroll
            for (int ni = 0; ni < 4; ++ni)
                acc[mi][ni] = MFMA16(af[mi], bfg[ni], acc[mi][ni]);
        __syncthreads();
    }

    const float* bias = (z == 0) ? bq : (z == 1) ? bk : bv;
#pragma unroll
    for (int mi = 0; mi < 4; ++mi) {
#pragma unroll
        for (int ni = 0; ni < 4; ++ni) {
            const int col = n0 + wc * 64 + ni * 16 + fr;
            const int hh = col >> 6, dd = col & 63;
#pragma unroll
            for (int j = 0; j < 4; ++j) {
                const int row = m0 + wr * 64 + mi * 16 + fq * 4 + j;
                float v = acc[mi][ni][j] + bias[col];
                const int nb = row >> 11, li = row & (SL - 1);
                const size_t off = (((size_t)nb * NH + hh) * SL + li) * HD + dd;
                if (z == 0) {
                    qh[off] = (bf16)(v * 0.125f);      // head_dim^-0.5
                } else if (z == 1) {
                    kh[off] = (bf16)v;
                } else {
                    vh[off] = (bf16)v;
                }
            }
        }
    }
}

// ------------------- output projection GEMM v2: A hi-only, W hi/lo (2 MFMA) -------------------
__global__ __launch_bounds__(256) void k_out_gemm(
    const bf16* __restrict__ ah,
    const bf16* __restrict__ wh, const bf16* __restrict__ wl,
    const float* __restrict__ bo, float* __restrict__ out)
{
    __shared__ __attribute__((aligned(16))) bf16 As[128 * 32];
    __shared__ __attribute__((aligned(16))) bf16 Bs[2][128 * 32];

    const int m0 = blockIdx.x * 128;
    const int n0 = blockIdx.y * 128;
    const int tid = threadIdx.x, wave = tid >> 6, lane = tid & 63;
    const int wr = wave >> 1, wc = wave & 1;
    const int fr = lane & 15, fq = lane >> 4;

    const f32x4 z4 = {0.f, 0.f, 0.f, 0.f};
    f32x4 acc[4][4];
#pragma unroll
    for (int i = 0; i < 4; ++i)
#pragma unroll
        for (int j = 0; j < 4; ++j) acc[i][j] = z4;

#pragma unroll 1
    for (int kk = 0; kk < ED; kk += 32) {
#pragma unroll
        for (int r = 0; r < 2; ++r) {
            const int chunk = r * 256 + tid;
            const int row = chunk >> 2, c8 = (chunk & 3) * 8;
            const size_t ax = (size_t)(m0 + row) * ED + kk + c8;
            const size_t bx = (size_t)(n0 + row) * ED + kk + c8;
            const int db = (r * 256 + wave * 64) * 8;
            gl_lds16(ah + ax, &As[db]);
            gl_lds16(wh + bx, &Bs[0][db]);
            gl_lds16(wl + bx, &Bs[1][db]);
        }
        __syncthreads();
        bf16x8 af[4], bfg[4][2];
#pragma unroll
        for (int i = 0; i < 4; ++i) {
            const int arow = wr * 64 + i * 16 + fr;
            af[i] = *(const bf16x8*)&As[arow * 32 + fq * 8];
            const int brow = wc * 64 + i * 16 + fr;
            bfg[i][0] = *(const bf16x8*)&Bs[0][brow * 32 + fq * 8];
            bfg[i][1] = *(const bf16x8*)&Bs[1][brow * 32 + fq * 8];
        }
#pragma unroll
        for (int mi = 0; mi < 4; ++mi)
#pragma unroll
            for (int ni = 0; ni < 4; ++ni) {
                acc[mi][ni] = MFMA16(af[mi], bfg[ni][0], acc[mi][ni]);
                acc[mi][ni] = MFMA16(af[mi], bfg[ni][1], acc[mi][ni]);
            }
        __syncthreads();
    }

#pragma unroll
    for (int mi = 0; mi < 4; ++mi)
#pragma unroll
        for (int ni = 0; ni < 4; ++ni) {
            const int col = n0 + wc * 64 + ni * 16 + fr;
#pragma unroll
            for (int j = 0; j < 4; ++j) {
                const int row = m0 + wr * 64 + mi * 16 + fq * 4 + j;
                out[(size_t)row * ED + col] = acc[mi][ni][j] + bo[col];
            }
        }
}

// ------------------- flash attention v12: v11 + fused mlg epilogue -------------------
__global__ __launch_bounds__(256) void k_flash(
    const bf16* __restrict__ qh, const bf16* __restrict__ kh,
    const bf16* __restrict__ vt,
    const float* __restrict__ bias, const int* __restrict__ mask,
    bf16* __restrict__ ch, float* __restrict__ mlg)
{
    __shared__ __attribute__((aligned(16))) bf16 Ks[2][64 * 64];  // [key][d] swz, dbuf
    __shared__ __attribute__((aligned(16))) bf16 Vs[2][64 * 64];  // [d][key] swz, dbuf
    __shared__ __attribute__((aligned(16))) bf16 Ws[4][16 * 64];  // per-wave P, swz

    const int bid = blockIdx.x;
    const int xcd = bid & 7, local = bid >> 3;
    const int h = xcd * 2 + (local >> 6);
    const int rem = local & 63;
    const int qt = rem >> 2, n = rem & 3;

    const int tid = threadIdx.x, wave = tid >> 6, lane = tid & 63;
    const int fr = lane & 15, fq = lane >> 4;
    const int frx = fr & 7;
    const int q0 = qt * 128;
    const int qw = q0 + wave * 32;                  // wave's 32-row base
    const size_t hoff = ((size_t)n * NH + h) * SL * HD;  // same value for vT base
    const f32x4 z4 = {0.f, 0.f, 0.f, 0.f};

    bf16x8 qf0[2], qf1[2];
#pragma unroll
    for (int m = 0; m < 2; ++m) {
        const size_t qb = hoff + (size_t)(qw + m * 16 + fr) * HD + fq * 8;
        qf0[m] = *(const bf16x8*)(qh + qb);
        qf1[m] = *(const bf16x8*)(qh + qb + 32);
    }

    f32x4 o[2][4];
#pragma unroll
    for (int m = 0; m < 2; ++m)
#pragma unroll
        for (int f = 0; f < 4; ++f) o[m][f] = z4;
    float mj[2][4], sj[2][4];   // sj: LANE-LOCAL partial sums
#pragma unroll
    for (int m = 0; m < 2; ++m)
#pragma unroll
        for (int j = 0; j < 4; ++j) { mj[m][j] = -3e38f; sj[m][j] = 0.f; }

    const int* mkb = mask + n * SL;
    const float* bh = bias + (size_t)h * SL * SL;

    auto stageK = [&](int kt2, int b) {
#pragma unroll
        for (int i = 0; i < 2; ++i) {
            const int li = i * 256 + tid;
            const int r = li >> 3, s = li & 7;
            gl_lds16(kh + hoff + (size_t)(kt2 * 64 + r) * HD + (s ^ (r & 7)) * 8,
                     &Ks[b][(i * 256 + wave * 64) * 8]);
        }
    };
    auto stageV = [&](int kt2, int b) {
#pragma unroll
        for (int i = 0; i < 2; ++i) {
            const int li = i * 256 + tid;
            const int r = li >> 3, s = li & 7;      // r = d row
            gl_lds16(vt + hoff + (size_t)r * SL + kt2 * 64 + (s ^ (r & 7)) * 8,
                     &Vs[b][(i * 256 + wave * 64) * 8]);
        }
    };

    // ---- prologue ----
    stageK(0, 0);
    stageV(0, 0);
    __syncthreads();   // drains K(0)+V(0) DMA

#pragma unroll 1
    for (int kt = 0; kt < 32; ++kt) {
        const int cur = kt & 1, nxt = cur ^ 1;
        const int kp1 = (kt < 31) ? kt + 1 : 31;

        // 0. mask bits for THIS tile
        const int mw0 = mkb[kt * 64 + fr];
        const int mw1 = mkb[kt * 64 + 16 + fr];
        const int mw2 = mkb[kt * 64 + 32 + fr];
        const int mw3 = mkb[kt * 64 + 48 + fr];

        // 1. issue next-tile K/V DMA
        stageK(kp1, nxt);
        stageV(kp1, nxt);
        const int mbits = (mw0 != 0 ? 1 : 0) | (mw1 != 0 ? 2 : 0)
                        | (mw2 != 0 ? 4 : 0) | (mw3 != 0 ? 8 : 0);

        // ---- compute: two independent 16-row chains ----
#pragma unroll
        for (int m = 0; m < 2; ++m) {
            float bfr[4][4];
#pragma unroll
            for (int nf = 0; nf < 4; ++nf)
#pragma unroll
                for (int j = 0; j < 4; ++j)
                    bfr[nf][j] = bh[(size_t)(qw + m * 16 + fq * 4 + j) * SL
                                    + kt * 64 + nf * 16 + fr];

            f32x4 sf[4];
            __builtin_amdgcn_s_setprio(1);
#pragma unroll
            for (int nf = 0; nf < 4; ++nf) {
                const bf16* kp = &Ks[cur][(nf * 16 + fr) * 64];
                const bf16x8 b0 = *(const bf16x8*)&kp[(fq ^ frx) * 8];
                const bf16x8 b1 = *(const bf16x8*)&kp[((fq + 4) ^ frx) * 8];
                f32x4 a = z4;
                a = MFMA16(qf0[m], b0, a);
                a = MFMA16(qf1[m], b1, a);
                sf[nf] = a;
            }
            __builtin_amdgcn_s_setprio(0);

            // bias + mask
#pragma unroll
            for (int nf = 0; nf < 4; ++nf) {
                const bool mk = (mbits >> nf) & 1;
#pragma unroll
                for (int j = 0; j < 4; ++j) {
                    float s = sf[nf][j] + bfr[nf][j];
                    sf[nf][j] = mk ? -1e30f : s;
                }
            }

            // defer-max online softmax (common path: no cross-lane ops)
            float tmax[4];
#pragma unroll
            for (int j = 0; j < 4; ++j)
                tmax[j] = fmaxf(fmaxf(sf[0][j], sf[1][j]), fmaxf(sf[2][j], sf[3][j]));
            bool need = false;
#pragma unroll
            for (int j = 0; j < 4; ++j)
                need = need || (tmax[j] > mj[m][j] + 8.0f);
            if (__any(need)) {
#pragma unroll
                for (int d = 1; d < 16; d <<= 1)
#pragma unroll
                    for (int j = 0; j < 4; ++j)
                        tmax[j] = fmaxf(tmax[j], __shfl_xor(tmax[j], d));
#pragma unroll
                for (int j = 0; j < 4; ++j) {
                    const float mn = fmaxf(mj[m][j], tmax[j]);
                    const float scale = __expf(mj[m][j] - mn);
                    mj[m][j] = mn;
                    sj[m][j] *= scale;
#pragma unroll
                    for (int f = 0; f < 4; ++f) o[m][f][j] *= scale;
                }
            }
#pragma unroll
            for (int nf = 0; nf < 4; ++nf)
#pragma unroll
                for (int j = 0; j < 4; ++j) {
                    const float w = __expf(sf[nf][j] - mj[m][j]);
                    sf[nf][j] = w;
                    sj[m][j] += w;
                }

            // P -> per-wave swizzled LDS tile (wave-local; reused across m)
#pragma unroll
            for (int nf = 0; nf < 4; ++nf)
#pragma unroll
                for (int j = 0; j < 4; ++j) {
                    const int row = fq * 4 + j, col = nf * 16 + fr;
                    Ws[wave][row * 64 + (((col >> 3) ^ (row & 7)) << 3) + (fr & 7)] =
                        (bf16)sf[nf][j];
                }
            const bf16* wp = &Ws[wave][fr * 64];
            const bf16x8 wa0 = *(const bf16x8*)&wp[(fq ^ frx) * 8];
            const bf16x8 wa1 = *(const bf16x8*)&wp[((fq + 4) ^ frx) * 8];
            __builtin_amdgcn_s_setprio(1);
#pragma unroll
            for (int f = 0; f < 4; ++f) {
                const bf16* vp = &Vs[cur][(f * 16 + fr) * 64];
                const bf16x8 vb0 = *(const bf16x8*)&vp[(fq ^ frx) * 8];
                const bf16x8 vb1 = *(const bf16x8*)&vp[((fq + 4) ^ frx) * 8];
                o[m][f] = MFMA16(wa0, vb0, o[m][f]);
                o[m][f] = MFMA16(wa1, vb1, o[m][f]);
            }
            __builtin_amdgcn_s_setprio(0);
        }

        __syncthreads();   // drains K/V(kt+1) DMA; fences buffer swap
    }

    // epilogue: reduce lane-local sj across the 16-lane row group (once)
#pragma unroll
    for (int m = 0; m < 2; ++m)
#pragma unroll
        for (int d = 1; d < 16; d <<= 1)
#pragma unroll
            for (int j = 0; j < 4; ++j)
                sj[m][j] += __shfl_xor(sj[m][j], d);

    // context (hi only) + fused mlg = m + ln(16 s)
#pragma unroll
    for (int m = 0; m < 2; ++m) {
#pragma unroll
        for (int j = 0; j < 4; ++j) {
            const float inv = 1.0f / sj[m][j];
            const int row = n * SL + qw + m * 16 + fq * 4 + j;
#pragma unroll
            for (int f = 0; f < 4; ++f) {
                const float v = o[m][f][j] * inv;
                const size_t off = (size_t)row * ED + h * HD + f * 16 + fr;
                ch[off] = (bf16)v;
            }
        }
        if (fr == 0) {
#pragma unroll
            for (int j = 0; j < 4; ++j) {
                const int r = qw + m * 16 + fq * 4 + j;
                mlg[((size_t)n * NH + h) * SL + r] =
                    mj[m][j] + __logf(16.0f * sj[m][j]);
            }
        }
    }
}

// ------------------- head-averaged weights v8: bf16 bias (reg-staged, padded) -------------------
// LDS 16+18 = 34 KB -> 4 blocks/CU resident; Bs2 stride 72 (144B) -> 2-way reads (free).
__global__ __launch_bounds__(256) void k_avg(
    const bf16* __restrict__ qh, const bf16* __restrict__ kh,
    const float* __restrict__ bias, const int* __restrict__ mask,
    const float* __restrict__ mlg, float* __restrict__ avg)
{
    __shared__ __attribute__((aligned(16))) bf16 Ks2[2][64 * 64];   // 16 KB
    __shared__ __attribute__((aligned(16))) bf16 Bs2[2][64 * 72];   // 18 KB, padded

    const int qt = blockIdx.x, kt = blockIdx.y;
    const int tid = threadIdx.x, wave = tid >> 6, lane = tid & 63;
    const int fr = lane & 15, fq = lane >> 4;
    const int frx = fr & 7;
    const int q0 = qt * 64, k0 = kt * 64;
    const int qr = q0 + wave * 16;
    const f32x4 z4 = {0.f, 0.f, 0.f, 0.f};

    f32x4 acc[4][4];
#pragma unroll
    for (int nn = 0; nn < 4; ++nn)
#pragma unroll
        for (int nf = 0; nf < 4; ++nf) acc[nn][nf] = z4;

    int mkbits = 0;
#pragma unroll
    for (int nn = 0; nn < 4; ++nn)
#pragma unroll
        for (int nf = 0; nf < 4; ++nf)
            mkbits |= (mask[nn * SL + k0 + nf * 16 + fr] != 0 ? 1 : 0) << (nn * 4 + nf);

    auto stageK = [&](int hh, int nn2, int b) {
        const bf16* kb = kh + (((size_t)nn2 * NH + hh) * SL + k0) * HD;
#pragma unroll
        for (int i = 0; i < 2; ++i) {
            const int li = i * 256 + tid;
            const int r = li >> 3, s = li & 7;
            gl_lds16(kb + (size_t)r * HD + (s ^ (r & 7)) * 8,
                     &Ks2[b][(i * 256 + wave * 64) * 8]);
        }
    };
    auto loadQ = [&](int hh, int nn2, bf16x8& a0, bf16x8& a1) {
        const bf16* qb = qh + ((((size_t)nn2 * NH + hh) * SL + qr + fr) * HD) + fq * 8;
        a0 = *(const bf16x8*)qb;
        a1 = *(const bf16x8*)(qb + 32);
    };
    auto loadMlg = [&](int hh, int nn2) -> f32x4 {
        return *(const f32x4*)(mlg + ((size_t)nn2 * NH + hh) * SL + qr + fq * 4);
    };

    // bias register staging: thread -> row tid>>2, cols (tid&3)*16..+16
    const int brow_t = tid >> 2, bcol_t = (tid & 3) * 16;
    f32x4 breg0, breg1, breg2, breg3;
    auto loadB = [&](int hh) {
        const float* bb = bias + (size_t)hh * SL * SL
                        + (size_t)(q0 + brow_t) * SL + k0 + bcol_t;
        breg0 = *(const f32x4*)bb;
        breg1 = *(const f32x4*)(bb + 4);
        breg2 = *(const f32x4*)(bb + 8);
        breg3 = *(const f32x4*)(bb + 12);
    };
    auto writeB = [&](int b) {
        bf16x8 w0, w1;
#pragma unroll
        for (int e = 0; e < 4; ++e) {
            w0[e]     = (bf16)breg0[e];
            w0[e + 4] = (bf16)breg1[e];
            w1[e]     = (bf16)breg2[e];
            w1[e + 4] = (bf16)breg3[e];
        }
        *(bf16x8*)&Bs2[b][brow_t * 72 + bcol_t] = w0;
        *(bf16x8*)&Bs2[b][brow_t * 72 + bcol_t + 8] = w1;
    };

    // prologue: K(0,0), bias(h=0); Q(0,0)+mlg(0,0) -> regs
    stageK(0, 0, 0);
    loadB(0);
    writeB(0);
    bf16x8 qcA, qcB;
    loadQ(0, 0, qcA, qcB);
    f32x4 mlgc = loadMlg(0, 0);
    __syncthreads();

#pragma unroll 1
    for (int h = 0; h < NH; ++h) {
        const int hb = h & 1;
#pragma unroll
        for (int nn = 0; nn < 4; ++nn) {
            const int ih = h * 4 + nn;           // unrolled: parity compile-time
            const int buf = ih & 1;

            // prefetch next step: K -> LDS, Q+mlg -> regs
            bf16x8 qnA, qnB;
            f32x4 mlgn = mlgc;
            if (ih < 63) {
                const int jh = (ih + 1) >> 2, jnn = (ih + 1) & 3;
                stageK(jh, jnn, buf ^ 1);
                loadQ(jh, jnn, qnA, qnB);
                mlgn = loadMlg(jh, jnn);
            } else {
                qnA = qcA; qnB = qcB;
            }
            // bias(h+1): issue loads at nn==0, convert+write at nn==3
            if (nn == 0 && h < NH - 1) loadB(h + 1);
            if (nn == 3 && h < NH - 1) writeB(hb ^ 1);

            // compute on current (qcA/qcB, Ks2[buf], Bs2[hb], mlgc)
#pragma unroll
            for (int nf = 0; nf < 4; ++nf) {
                const bf16* kp = &Ks2[buf][(nf * 16 + fr) * 64];
                const bf16x8 b0 = *(const bf16x8*)&kp[(fq ^ frx) * 8];
                const bf16x8 b1 = *(const bf16x8*)&kp[((fq + 4) ^ frx) * 8];
                f32x4 a = z4;
                a = MFMA16(qcA, b0, a);
                a = MFMA16(qcB, b1, a);
                const bool mk = (mkbits >> (nn * 4 + nf)) & 1;
#pragma unroll
                for (int j = 0; j < 4; ++j) {
                    const float bb =
                        (float)Bs2[hb][(wave * 16 + fq * 4 + j) * 72 + nf * 16 + fr];
                    const float w = mk ? 0.f : __expf(a[j] + bb - mlgc[j]);
                    acc[nn][nf][j] += w;
                }
            }
            __syncthreads();    // drains next K DMA; fences buffer swap + Bs2 write
            qcA = qnA; qcB = qnB; mlgc = mlgn;
        }
    }

#pragma unroll
    for (int nn = 0; nn < 4; ++nn)
#pragma unroll
        for (int j = 0; j < 4; ++j) {
            const size_t rowoff = ((size_t)nn * SL + qr + fq * 4 + j) * SL;
#pragma unroll
            for (int nf = 0; nf < 4; ++nf)
                avg[rowoff + k0 + nf * 16 + fr] = acc[nn][nf][j];
        }
}

// ------------------- launcher -------------------
extern "C" void kernel_launch(void* const* d_in, const int* in_sizes, int n_in,
                              void* d_out, int out_size, void* d_ws, size_t ws_size,
                              hipStream_t stream)
{
    (void)in_sizes; (void)n_in; (void)out_size; (void)ws_size;
    const float* query = (const float*)d_in[0];
    const float* bias  = (const float*)d_in[1];
    const int* mask = (const int*)d_in[2];
    const float* Wq = (const float*)d_in[3];
    const float* bq = (const float*)d_in[4];
    const float* Wk = (const float*)d_in[5];
    const float* bk = (const float*)d_in[6];
    const float* Wv = (const float*)d_in[7];
    const float* bv = (const float*)d_in[8];
    const float* Wo = (const float*)d_in[9];
    const float* bo = (const float*)d_in[10];
    float* out0 = (float*)d_out;                      // [N,L,E]
    float* out1 = out0 + (size_t)MR * ED;             // [N,L,L]

    char* p = (char*)d_ws;
    auto carve = [&](size_t bytes) {
        char* r = p;
        p += (bytes + 255) & ~(size_t)255;
        return r;
    };
    const size_t QKVB = (size_t)NB * NH * SL * HD * 2;   // 16.78 MB
    bf16* xh = (bf16*)carve((size_t)MR * ED * 2);
    bf16* wqkv = (bf16*)carve((size_t)3 * ED * ED * 2);  // hi-only Wq,Wk,Wv
    bf16* woh = (bf16*)carve((size_t)ED * ED * 2);
    bf16* wol = (bf16*)carve((size_t)ED * ED * 2);
    bf16* qh = (bf16*)carve(QKVB);
    bf16* kh = (bf16*)carve(QKVB);
    bf16* vh = (bf16*)carve(QKVB);
    bf16* vtb = (bf16*)carve(QKVB);
    float* mlg  = (float*)carve((size_t)NB * NH * SL * 4);
    bf16* ch = (bf16*)carve((size_t)MR * ED * 2);

    // 1. casts/splits
    {
        const int n4 = MR * ED / 4;
        k_cast<<<(n4 + 255) / 256, 256, 0, stream>>>(query, xh, n4);
        const int w4 = ED * ED / 4;
        const float* Ws3[3] = {Wq, Wk, Wv};
        for (int i = 0; i < 3; ++i)
            k_cast<<<(w4 + 255) / 256, 256, 0, stream>>>(
                Ws3[i], wqkv + (size_t)i * ED * ED, w4);
        k_split<<<(w4 + 255) / 256, 256, 0, stream>>>(Wo, woh, wol, w4);
    }
    // 2. QKV projections (hi-only)
    k_qkv_gemm<<<dim3(MR / 128, ED / 128, 3), 256, 0, stream>>>(
        xh, wqkv, bq, bk, bv, qh, kh, vh);
    // 2b. V transpose -> [n,h,d,key]
    k_vt<<<dim3(SL / 256, NH, NB), 256, 0, stream>>>(vh, vtb);
    // 3. flash attention + context + fused mlg (QBLK=128 -> 1024 blocks)
    k_flash<<<dim3(1024), 256, 0, stream>>>(
        qh, kh, vtb, bias, mask, ch, mlg);
    // 4. head-averaged attention weights (64x64 tiles)
    k_avg<<<dim3(SL / 64, SL / 64), 256, 0, stream>>>(
        qh, kh, bias, mask, mlg, out1);
    // 5. output projection (A hi, W hi/lo)
    k_out_gemm<<<dim3(MR / 128, ED / 128), 256, 0, stream>>>(
        ch, woh, wol, bo, out0);
}

// Round 22
// 581.853 us; speedup vs baseline: 1.0151x; 1.0151x over previous
//
#include <hip/hip_runtime.h>
#include <stdint.h>

typedef __bf16 bf16;
typedef __bf16 bf16x4 __attribute__((ext_vector_type(4)));
typedef __bf16 bf16x8 __attribute__((ext_vector_type(8)));
typedef float f32x4 __attribute__((ext_vector_type(4)));

#define MFMA16(a, b, c) __builtin_amdgcn_mfma_f32_16x16x32_bf16((a), (b), (c), 0, 0, 0)

static constexpr int NB = 4;      // batch
static constexpr int NH = 16;     // heads
static constexpr int SL = 2048;   // seq len
static constexpr int HD = 64;     // head dim
static constexpr int ED = 1024;   // embed
static constexpr int MR = NB * SL; // 8192 rows

__device__ __forceinline__ void gl_lds16(const void* g, void* l) {
    __builtin_amdgcn_global_load_lds(
        (const __attribute__((address_space(1))) unsigned int*)g,
        (__attribute__((address_space(3))) unsigned int*)l, 16, 0, 0);
}

// ------------------- f32 -> bf16 hi/lo split -------------------
__global__ void k_split(const float* __restrict__ src, bf16* __restrict__ hi,
                        bf16* __restrict__ lo, int n4) {
    int i = blockIdx.x * blockDim.x + threadIdx.x;
    if (i >= n4) return;
    const float4 v = ((const float4*)src)[i];
    float vv[4] = {v.x, v.y, v.z, v.w};
    bf16x4 hv, lv;
#pragma unroll
    for (int e = 0; e < 4; ++e) {
        bf16 h = (bf16)vv[e];
        hv[e] = h;
        lv[e] = (bf16)(vv[e] - (float)h);
    }
    ((bf16x4*)hi)[i] = hv;
    ((bf16x4*)lo)[i] = lv;
}

// ------------------- f32 -> bf16 plain cast -------------------
__global__ void k_cast(const float* __restrict__ src, bf16* __restrict__ dst, int n4) {
    int i = blockIdx.x * blockDim.x + threadIdx.x;
    if (i >= n4) return;
    const float4 v = ((const float4*)src)[i];
    bf16x4 hv = {(bf16)v.x, (bf16)v.y, (bf16)v.z, (bf16)v.w};
    ((bf16x4*)dst)[i] = hv;
}

// ------------------- V transpose: [n,h,key,d] -> [n,h,d,key] -------------------
__global__ __launch_bounds__(256) void k_vt(const bf16* __restrict__ v,
                                            bf16* __restrict__ vt) {
    __shared__ bf16 T[256 * 72];   // [key_local][d] padded (+8)
    const int n = blockIdx.z, h = blockIdx.y, kc = blockIdx.x * 256;
    const int tid = threadIdx.x;
    const size_t base1 = ((size_t)n * NH + h) * SL * HD;
    const size_t base2 = ((size_t)n * NH + h) * HD * SL;

#pragma unroll
    for (int ri = 0; ri < 8; ++ri) {
        const int kl = ri * 32 + (tid >> 3), d0 = (tid & 7) * 8;
        const bf16x8 x = *(const bf16x8*)(v + base1 + (size_t)(kc + kl) * HD + d0);
        *(bf16x8*)&T[kl * 72 + d0] = x;
    }
    __syncthreads();

    const int d = tid >> 2, kch = (tid & 3) * 64;
#pragma unroll
    for (int i = 0; i < 8; ++i) {
        bf16x8 y;
#pragma unroll
        for (int e = 0; e < 8; ++e)
            y[e] = T[(kch + i * 8 + e) * 72 + d];
        *(bf16x8*)(vt + base2 + (size_t)d * SL + kc + kch + i * 8) = y;
    }
}

// ------------------- QKV projection GEMM v2: hi-only (1 MFMA/pair) -------------------
__global__ __launch_bounds__(256) void k_qkv_gemm(
    const bf16* __restrict__ xh, const bf16* __restrict__ wh,
    const float* __restrict__ bq, const float* __restrict__ bk,
    const float* __restrict__ bv,
    bf16* __restrict__ qh, bf16* __restrict__ kh, bf16* __restrict__ vh)
{
    __shared__ __attribute__((aligned(16))) bf16 As[128 * 32];
    __shared__ __attribute__((aligned(16))) bf16 Bs[128 * 32];

    const int z  = blockIdx.z;           // 0=q,1=k,2=v
    const int m0 = blockIdx.x * 128;
    const int n0 = blockIdx.y * 128;
    const int tid = threadIdx.x, wave = tid >> 6, lane = tid & 63;
    const int wr = wave >> 1, wc = wave & 1;
    const int fr = lane & 15, fq = lane >> 4;
    const bf16* Wh = wh + (size_t)z * ED * ED;

    const f32x4 z4 = {0.f, 0.f, 0.f, 0.f};
    f32x4 acc[4][4];
#pragma unroll
    for (int i = 0; i < 4; ++i)
#pragma unroll
        for (int j = 0; j < 4; ++j) acc[i][j] = z4;

#pragma unroll 1
    for (int kk = 0; kk < ED; kk += 32) {
#pragma unroll
        for (int r = 0; r < 2; ++r) {
            const int chunk = r * 256 + tid;
            const int row = chunk >> 2, c8 = (chunk & 3) * 8;
            const size_t ax = (size_t)(m0 + row) * ED + kk + c8;
            const size_t bx = (size_t)(n0 + row) * ED + kk + c8;
            const int db = (r * 256 + wave * 64) * 8;   // wave-uniform LDS base
            gl_lds16(xh + ax, &As[db]);
            gl_lds16(Wh + bx, &Bs[db]);
        }
        __syncthreads();
        bf16x8 af[4], bfg[4];
#pragma unroll
        for (int i = 0; i < 4; ++i) {
            const int arow = wr * 64 + i * 16 + fr;
            af[i] = *(const bf16x8*)&As[arow * 32 + fq * 8];
            const int brow = wc * 64 + i * 16 + fr;
            bfg[i] = *(const bf16x8*)&Bs[brow * 32 + fq * 8];
        }
#pragma unroll
        for (int mi = 0; mi < 4; ++mi)
#pragma unroll
            for (int ni = 0; ni < 4; ++ni)
                acc[mi][ni] = MFMA16(af[mi], bfg[ni], acc[mi][ni]);
        __syncthreads();
    }

    const float* bias = (z == 0) ? bq : (z == 1) ? bk : bv;
#pragma unroll
    for (int mi = 0; mi < 4; ++mi) {
#pragma unroll
        for (int ni = 0; ni < 4; ++ni) {
            const int col = n0 + wc * 64 + ni * 16 + fr;
            const int hh = col >> 6, dd = col & 63;
#pragma unroll
            for (int j = 0; j < 4; ++j) {
                const int row = m0 + wr * 64 + mi * 16 + fq * 4 + j;
                float v = acc[mi][ni][j] + bias[col];
                const int nb = row >> 11, li = row & (SL - 1);
                const size_t off = (((size_t)nb * NH + hh) * SL + li) * HD + dd;
                if (z == 0) {
                    qh[off] = (bf16)(v * 0.125f);      // head_dim^-0.5
                } else if (z == 1) {
                    kh[off] = (bf16)v;
                } else {
                    vh[off] = (bf16)v;
                }
            }
        }
    }
}

// ------------------- output projection GEMM v2: A hi-only, W hi/lo (2 MFMA) -------------------
__global__ __launch_bounds__(256) void k_out_gemm(
    const bf16* __restrict__ ah,
    const bf16* __restrict__ wh, const bf16* __restrict__ wl,
    const float* __restrict__ bo, float* __restrict__ out)
{
    __shared__ __attribute__((aligned(16))) bf16 As[128 * 32];
    __shared__ __attribute__((aligned(16))) bf16 Bs[2][128 * 32];

    const int m0 = blockIdx.x * 128;
    const int n0 = blockIdx.y * 128;
    const int tid = threadIdx.x, wave = tid >> 6, lane = tid & 63;
    const int wr = wave >> 1, wc = wave & 1;
    const int fr = lane & 15, fq = lane >> 4;

    const f32x4 z4 = {0.f, 0.f, 0.f, 0.f};
    f32x4 acc[4][4];
#pragma unroll
    for (int i = 0; i < 4; ++i)
#pragma unroll
        for (int j = 0; j < 4; ++j) acc[i][j] = z4;

#pragma unroll 1
    for (int kk = 0; kk < ED; kk += 32) {
#pragma unroll
        for (int r = 0; r < 2; ++r) {
            const int chunk = r * 256 + tid;
            const int row = chunk >> 2, c8 = (chunk & 3) * 8;
            const size_t ax = (size_t)(m0 + row) * ED + kk + c8;
            const size_t bx = (size_t)(n0 + row) * ED + kk + c8;
            const int db = (r * 256 + wave * 64) * 8;
            gl_lds16(ah + ax, &As[db]);
            gl_lds16(wh + bx, &Bs[0][db]);
            gl_lds16(wl + bx, &Bs[1][db]);
        }
        __syncthreads();
        bf16x8 af[4], bfg[4][2];
#pragma unroll
        for (int i = 0; i < 4; ++i) {
            const int arow = wr * 64 + i * 16 + fr;
            af[i] = *(const bf16x8*)&As[arow * 32 + fq * 8];
            const int brow = wc * 64 + i * 16 + fr;
            bfg[i][0] = *(const bf16x8*)&Bs[0][brow * 32 + fq * 8];
            bfg[i][1] = *(const bf16x8*)&Bs[1][brow * 32 + fq * 8];
        }
#pragma unroll
        for (int mi = 0; mi < 4; ++mi)
#pragma unroll
            for (int ni = 0; ni < 4; ++ni) {
                acc[mi][ni] = MFMA16(af[mi], bfg[ni][0], acc[mi][ni]);
                acc[mi][ni] = MFMA16(af[mi], bfg[ni][1], acc[mi][ni]);
            }
        __syncthreads();
    }

#pragma unroll
    for (int mi = 0; mi < 4; ++mi)
#pragma unroll
        for (int ni = 0; ni < 4; ++ni) {
            const int col = n0 + wc * 64 + ni * 16 + fr;
#pragma unroll
            for (int j = 0; j < 4; ++j) {
                const int row = m0 + wr * 64 + mi * 16 + fq * 4 + j;
                out[(size_t)row * ED + col] = acc[mi][ni][j] + bo[col];
            }
        }
}

// ------------------- flash attention v12: DMA-staged K/V + fused mlg epilogue -------------------
__global__ __launch_bounds__(256) void k_flash(
    const bf16* __restrict__ qh, const bf16* __restrict__ kh,
    const bf16* __restrict__ vt,
    const float* __restrict__ bias, const int* __restrict__ mask,
    bf16* __restrict__ ch, float* __restrict__ mlg)
{
    __shared__ __attribute__((aligned(16))) bf16 Ks[2][64 * 64];  // [key][d] swz, dbuf
    __shared__ __attribute__((aligned(16))) bf16 Vs[2][64 * 64];  // [d][key] swz, dbuf
    __shared__ __attribute__((aligned(16))) bf16 Ws[4][16 * 64];  // per-wave P, swz

    const int bid = blockIdx.x;
    const int xcd = bid & 7, local = bid >> 3;
    const int h = xcd * 2 + (local >> 6);
    const int rem = local & 63;
    const int qt = rem >> 2, n = rem & 3;

    const int tid = threadIdx.x, wave = tid >> 6, lane = tid & 63;
    const int fr = lane & 15, fq = lane >> 4;
    const int frx = fr & 7;
    const int q0 = qt * 128;
    const int qw = q0 + wave * 32;                  // wave's 32-row base
    const size_t hoff = ((size_t)n * NH + h) * SL * HD;  // same value for vT base
    const f32x4 z4 = {0.f, 0.f, 0.f, 0.f};

    bf16x8 qf0[2], qf1[2];
#pragma unroll
    for (int m = 0; m < 2; ++m) {
        const size_t qb = hoff + (size_t)(qw + m * 16 + fr) * HD + fq * 8;
        qf0[m] = *(const bf16x8*)(qh + qb);
        qf1[m] = *(const bf16x8*)(qh + qb + 32);
    }

    f32x4 o[2][4];
#pragma unroll
    for (int m = 0; m < 2; ++m)
#pragma unroll
        for (int f = 0; f < 4; ++f) o[m][f] = z4;
    float mj[2][4], sj[2][4];   // sj: LANE-LOCAL partial sums
#pragma unroll
    for (int m = 0; m < 2; ++m)
#pragma unroll
        for (int j = 0; j < 4; ++j) { mj[m][j] = -3e38f; sj[m][j] = 0.f; }

    const int* mkb = mask + n * SL;
    const float* bh = bias + (size_t)h * SL * SL;

    auto stageK = [&](int kt2, int b) {
#pragma unroll
        for (int i = 0; i < 2; ++i) {
            const int li = i * 256 + tid;
            const int r = li >> 3, s = li & 7;
            gl_lds16(kh + hoff + (size_t)(kt2 * 64 + r) * HD + (s ^ (r & 7)) * 8,
                     &Ks[b][(i * 256 + wave * 64) * 8]);
        }
    };
    auto stageV = [&](int kt2, int b) {
#pragma unroll
        for (int i = 0; i < 2; ++i) {
            const int li = i * 256 + tid;
            const int r = li >> 3, s = li & 7;      // r = d row
            gl_lds16(vt + hoff + (size_t)r * SL + kt2 * 64 + (s ^ (r & 7)) * 8,
                     &Vs[b][(i * 256 + wave * 64) * 8]);
        }
    };

    // ---- prologue ----
    stageK(0, 0);
    stageV(0, 0);
    __syncthreads();   // drains K(0)+V(0) DMA

#pragma unroll 1
    for (int kt = 0; kt < 32; ++kt) {
        const int cur = kt & 1, nxt = cur ^ 1;
        const int kp1 = (kt < 31) ? kt + 1 : 31;

        // 0. mask bits for THIS tile
        const int mw0 = mkb[kt * 64 + fr];
        const int mw1 = mkb[kt * 64 + 16 + fr];
        const int mw2 = mkb[kt * 64 + 32 + fr];
        const int mw3 = mkb[kt * 64 + 48 + fr];

        // 1. issue next-tile K/V DMA
        stageK(kp1, nxt);
        stageV(kp1, nxt);
        const int mbits = (mw0 != 0 ? 1 : 0) | (mw1 != 0 ? 2 : 0)
                        | (mw2 != 0 ? 4 : 0) | (mw3 != 0 ? 8 : 0);

        // ---- compute: two independent 16-row chains ----
#pragma unroll
        for (int m = 0; m < 2; ++m) {
            float bfr[4][4];
#pragma unroll
            for (int nf = 0; nf < 4; ++nf)
#pragma unroll
                for (int j = 0; j < 4; ++j)
                    bfr[nf][j] = bh[(size_t)(qw + m * 16 + fq * 4 + j) * SL
                                    + kt * 64 + nf * 16 + fr];

            f32x4 sf[4];
            __builtin_amdgcn_s_setprio(1);
#pragma unroll
            for (int nf = 0; nf < 4; ++nf) {
                const bf16* kp = &Ks[cur][(nf * 16 + fr) * 64];
                const bf16x8 b0 = *(const bf16x8*)&kp[(fq ^ frx) * 8];
                const bf16x8 b1 = *(const bf16x8*)&kp[((fq + 4) ^ frx) * 8];
                f32x4 a = z4;
                a = MFMA16(qf0[m], b0, a);
                a = MFMA16(qf1[m], b1, a);
                sf[nf] = a;
            }
            __builtin_amdgcn_s_setprio(0);

            // bias + mask
#pragma unroll
            for (int nf = 0; nf < 4; ++nf) {
                const bool mk = (mbits >> nf) & 1;
#pragma unroll
                for (int j = 0; j < 4; ++j) {
                    float s = sf[nf][j] + bfr[nf][j];
                    sf[nf][j] = mk ? -1e30f : s;
                }
            }

            // defer-max online softmax (common path: no cross-lane ops)
            float tmax[4];
#pragma unroll
            for (int j = 0; j < 4; ++j)
                tmax[j] = fmaxf(fmaxf(sf[0][j], sf[1][j]), fmaxf(sf[2][j], sf[3][j]));
            bool need = false;
#pragma unroll
            for (int j = 0; j < 4; ++j)
                need = need || (tmax[j] > mj[m][j] + 8.0f);
            if (__any(need)) {
#pragma unroll
                for (int d = 1; d < 16; d <<= 1)
#pragma unroll
                    for (int j = 0; j < 4; ++j)
                        tmax[j] = fmaxf(tmax[j], __shfl_xor(tmax[j], d));
#pragma unroll
                for (int j = 0; j < 4; ++j) {
                    const float mn = fmaxf(mj[m][j], tmax[j]);
                    const float scale = __expf(mj[m][j] - mn);
                    mj[m][j] = mn;
                    sj[m][j] *= scale;
#pragma unroll
                    for (int f = 0; f < 4; ++f) o[m][f][j] *= scale;
                }
            }
#pragma unroll
            for (int nf = 0; nf < 4; ++nf)
#pragma unroll
                for (int j = 0; j < 4; ++j) {
                    const float w = __expf(sf[nf][j] - mj[m][j]);
                    sf[nf][j] = w;
                    sj[m][j] += w;
                }

            // P -> per-wave swizzled LDS tile (wave-local; reused across m)
#pragma unroll
            for (int nf = 0; nf < 4; ++nf)
#pragma unroll
                for (int j = 0; j < 4; ++j) {
                    const int row = fq * 4 + j, col = nf * 16 + fr;
                    Ws[wave][row * 64 + (((col >> 3) ^ (row & 7)) << 3) + (fr & 7)] =
                        (bf16)sf[nf][j];
                }
            const bf16* wp = &Ws[wave][fr * 64];
            const bf16x8 wa0 = *(const bf16x8*)&wp[(fq ^ frx) * 8];
            const bf16x8 wa1 = *(const bf16x8*)&wp[((fq + 4) ^ frx) * 8];
            __builtin_amdgcn_s_setprio(1);
#pragma unroll
            for (int f = 0; f < 4; ++f) {
                const bf16* vp = &Vs[cur][(f * 16 + fr) * 64];
                const bf16x8 vb0 = *(const bf16x8*)&vp[(fq ^ frx) * 8];
                const bf16x8 vb1 = *(const bf16x8*)&vp[((fq + 4) ^ frx) * 8];
                o[m][f] = MFMA16(wa0, vb0, o[m][f]);
                o[m][f] = MFMA16(wa1, vb1, o[m][f]);
            }
            __builtin_amdgcn_s_setprio(0);
        }

        __syncthreads();   // drains K/V(kt+1) DMA; fences buffer swap
    }

    // epilogue: reduce lane-local sj across the 16-lane row group (once)
#pragma unroll
    for (int m = 0; m < 2; ++m)
#pragma unroll
        for (int d = 1; d < 16; d <<= 1)
#pragma unroll
            for (int j = 0; j < 4; ++j)
                sj[m][j] += __shfl_xor(sj[m][j], d);

    // context (hi only) + fused mlg = m + ln(16 s)
#pragma unroll
    for (int m = 0; m < 2; ++m) {
#pragma unroll
        for (int j = 0; j < 4; ++j) {
            const float inv = 1.0f / sj[m][j];
            const int row = n * SL + qw + m * 16 + fq * 4 + j;
#pragma unroll
            for (int f = 0; f < 4; ++f) {
                const float v = o[m][f][j] * inv;
                const size_t off = (size_t)row * ED + h * HD + f * 16 + fr;
                ch[off] = (bf16)v;
            }
        }
        if (fr == 0) {
#pragma unroll
            for (int j = 0; j < 4; ++j) {
                const int r = qw + m * 16 + fq * 4 + j;
                mlg[((size_t)n * NH + h) * SL + r] =
                    mj[m][j] + __logf(16.0f * sj[m][j]);
            }
        }
    }
}

// ------------------- head-averaged weights v7.1 (round-20 measured-best) -------------------
__global__ __launch_bounds__(256) void k_avg(
    const bf16* __restrict__ qh, const bf16* __restrict__ kh,
    const float* __restrict__ bias, const int* __restrict__ mask,
    const float* __restrict__ mlg, float* __restrict__ avg)
{
    __shared__ __attribute__((aligned(16))) bf16 Ks2[2][64 * 64];   // 16 KB
    __shared__ __attribute__((aligned(16))) float Bs2[2][64 * 64];  // 32 KB

    const int qt = blockIdx.x, kt = blockIdx.y;
    const int tid = threadIdx.x, wave = tid >> 6, lane = tid & 63;
    const int fr = lane & 15, fq = lane >> 4;
    const int frx = fr & 7;
    const int q0 = qt * 64, k0 = kt * 64;
    const int qr = q0 + wave * 16;
    const f32x4 z4 = {0.f, 0.f, 0.f, 0.f};

    f32x4 acc[4][4];
#pragma unroll
    for (int nn = 0; nn < 4; ++nn)
#pragma unroll
        for (int nf = 0; nf < 4; ++nf) acc[nn][nf] = z4;

    int mkbits = 0;
#pragma unroll
    for (int nn = 0; nn < 4; ++nn)
#pragma unroll
        for (int nf = 0; nf < 4; ++nf)
            mkbits |= (mask[nn * SL + k0 + nf * 16 + fr] != 0 ? 1 : 0) << (nn * 4 + nf);

    auto stageK = [&](int hh, int nn2, int b) {
        const bf16* kb = kh + (((size_t)nn2 * NH + hh) * SL + k0) * HD;
#pragma unroll
        for (int i = 0; i < 2; ++i) {
            const int li = i * 256 + tid;
            const int r = li >> 3, s = li & 7;
            gl_lds16(kb + (size_t)r * HD + (s ^ (r & 7)) * 8,
                     &Ks2[b][(i * 256 + wave * 64) * 8]);
        }
    };
    auto stageB = [&](int hh, int b) {   // 64x64 f32 bias tile, 4 chunks
        const float* bb = bias + (size_t)hh * SL * SL + (size_t)q0 * SL + k0;
#pragma unroll
        for (int i = 0; i < 4; ++i) {
            const int li = i * 256 + tid;
            const int r = li >> 4, c = li & 15;
            gl_lds16(bb + (size_t)r * SL + c * 4,
                     &Bs2[b][(i * 256 + wave * 64) * 4]);
        }
    };
    auto loadQ = [&](int hh, int nn2, bf16x8& a0, bf16x8& a1) {
        const bf16* qb = qh + ((((size_t)nn2 * NH + hh) * SL + qr + fr) * HD) + fq * 8;
        a0 = *(const bf16x8*)qb;
        a1 = *(const bf16x8*)(qb + 32);
    };
    auto loadMlg = [&](int hh, int nn2) -> f32x4 {
        return *(const f32x4*)(mlg + ((size_t)nn2 * NH + hh) * SL + qr + fq * 4);
    };

    // prologue: K(0,0), bias(h=0); Q(0,0)+mlg(0,0) -> regs
    stageK(0, 0, 0);
    stageB(0, 0);
    bf16x8 qcA, qcB;
    loadQ(0, 0, qcA, qcB);
    f32x4 mlgc = loadMlg(0, 0);
    __syncthreads();

#pragma unroll 1
    for (int h = 0; h < NH; ++h) {
        const int hb = h & 1;
#pragma unroll
        for (int nn = 0; nn < 4; ++nn) {
            const int ih = h * 4 + nn;           // unrolled: parity compile-time
            const int buf = ih & 1;

            // prefetch next step: K -> LDS, Q+mlg -> regs; bias(h+1) at nn==0
            bf16x8 qnA, qnB;
            f32x4 mlgn = mlgc;
            if (ih < 63) {
                const int jh = (ih + 1) >> 2, jnn = (ih + 1) & 3;
                stageK(jh, jnn, buf ^ 1);
                loadQ(jh, jnn, qnA, qnB);
                mlgn = loadMlg(jh, jnn);
            } else {
                qnA = qcA; qnB = qcB;
            }
            if (nn == 0 && h < NH - 1) stageB(h + 1, hb ^ 1);

            // compute on current (qcA/qcB, Ks2[buf], Bs2[hb], mlgc)
#pragma unroll
            for (int nf = 0; nf < 4; ++nf) {
                const bf16* kp = &Ks2[buf][(nf * 16 + fr) * 64];
                const bf16x8 b0 = *(const bf16x8*)&kp[(fq ^ frx) * 8];
                const bf16x8 b1 = *(const bf16x8*)&kp[((fq + 4) ^ frx) * 8];
                f32x4 a = z4;
                a = MFMA16(qcA, b0, a);
                a = MFMA16(qcB, b1, a);
                const bool mk = (mkbits >> (nn * 4 + nf)) & 1;
#pragma unroll
                for (int j = 0; j < 4; ++j) {
                    const float w = mk ? 0.f
                        : __expf(a[j] + Bs2[hb][(wave * 16 + fq * 4 + j) * 64
                                                + nf * 16 + fr]
                                 - mlgc[j]);
                    acc[nn][nf][j] += w;
                }
            }
            __syncthreads();    // drains next K (+bias) DMA; fences swap
            qcA = qnA; qcB = qnB; mlgc = mlgn;
        }
    }

#pragma unroll
    for (int nn = 0; nn < 4; ++nn)
#pragma unroll
        for (int j = 0; j < 4; ++j) {
            const size_t rowoff = ((size_t)nn * SL + qr + fq * 4 + j) * SL;
#pragma unroll
            for (int nf = 0; nf < 4; ++nf)
                avg[rowoff + k0 + nf * 16 + fr] = acc[nn][nf][j];
        }
}

// ------------------- launcher -------------------
extern "C" void kernel_launch(void* const* d_in, const int* in_sizes, int n_in,
                              void* d_out, int out_size, void* d_ws, size_t ws_size,
                              hipStream_t stream)
{
    (void)in_sizes; (void)n_in; (void)out_size; (void)ws_size;
    const float* query = (const float*)d_in[0];
    const float* bias  = (const float*)d_in[1];
    const int* mask = (const int*)d_in[2];
    const float* Wq = (const float*)d_in[3];
    const float* bq = (const float*)d_in[4];
    const float* Wk = (const float*)d_in[5];
    const float* bk = (const float*)d_in[6];
    const float* Wv = (const float*)d_in[7];
    const float* bv = (const float*)d_in[8];
    const float* Wo = (const float*)d_in[9];
    const float* bo = (const float*)d_in[10];
    float* out0 = (float*)d_out;                      // [N,L,E]
    float* out1 = out0 + (size_t)MR * ED;             // [N,L,L]

    char* p = (char*)d_ws;
    auto carve = [&](size_t bytes) {
        char* r = p;
        p += (bytes + 255) & ~(size_t)255;
        return r;
    };
    const size_t QKVB = (size_t)NB * NH * SL * HD * 2;   // 16.78 MB
    bf16* xh = (bf16*)carve((size_t)MR * ED * 2);
    bf16* wqkv = (bf16*)carve((size_t)3 * ED * ED * 2);  // hi-only Wq,Wk,Wv
    bf16* woh = (bf16*)carve((size_t)ED * ED * 2);
    bf16* wol = (bf16*)carve((size_t)ED * ED * 2);
    bf16* qh = (bf16*)carve(QKVB);
    bf16* kh = (bf16*)carve(QKVB);
    bf16* vh = (bf16*)carve(QKVB);
    bf16* vtb = (bf16*)carve(QKVB);
    float* mlg  = (float*)carve((size_t)NB * NH * SL * 4);
    bf16* ch = (bf16*)carve((size_t)MR * ED * 2);

    // 1. casts/splits
    {
        const int n4 = MR * ED / 4;
        k_cast<<<(n4 + 255) / 256, 256, 0, stream>>>(query, xh, n4);
        const int w4 = ED * ED / 4;
        const float* Ws3[3] = {Wq, Wk, Wv};
        for (int i = 0; i < 3; ++i)
            k_cast<<<(w4 + 255) / 256, 256, 0, stream>>>(
                Ws3[i], wqkv + (size_t)i * ED * ED, w4);
        k_split<<<(w4 + 255) / 256, 256, 0, stream>>>(Wo, woh, wol, w4);
    }
    // 2. QKV projections (hi-only)
    k_qkv_gemm<<<dim3(MR / 128, ED / 128, 3), 256, 0, stream>>>(
        xh, wqkv, bq, bk, bv, qh, kh, vh);
    // 2b. V transpose -> [n,h,d,key]
    k_vt<<<dim3(SL / 256, NH, NB), 256, 0, stream>>>(vh, vtb);
    // 3. flash attention + context + fused mlg (QBLK=128 -> 1024 blocks)
    k_flash<<<dim3(1024), 256, 0, stream>>>(
        qh, kh, vtb, bias, mask, ch, mlg);
    // 4. head-averaged attention weights (64x64 tiles)
    k_avg<<<dim3(SL / 64, SL / 64), 256, 0, stream>>>(
        qh, kh, bias, mask, mlg, out1);
    // 5. output projection (A hi, W hi/lo)
    k_out_gemm<<<dim3(MR / 128, ED / 128), 256, 0, stream>>>(
        ch, woh, wol, bo, out0);
}

// Round 24
// 570.392 us; speedup vs baseline: 1.0355x; 1.0201x over previous
//
#include <hip/hip_runtime.h>
#include <stdint.h>

typedef __bf16 bf16;
typedef __bf16 bf16x4 __attribute__((ext_vector_type(4)));
typedef __bf16 bf16x8 __attribute__((ext_vector_type(8)));
typedef float f32x4 __attribute__((ext_vector_type(4)));

#define MFMA16(a, b, c) __builtin_amdgcn_mfma_f32_16x16x32_bf16((a), (b), (c), 0, 0, 0)

static constexpr int NB = 4;      // batch
static constexpr int NH = 16;     // heads
static constexpr int SL = 2048;   // seq len
static constexpr int HD = 64;     // head dim
static constexpr int ED = 1024;   // embed
static constexpr int MR = NB * SL; // 8192 rows

__device__ __forceinline__ void gl_lds16(const void* g, void* l) {
    __builtin_amdgcn_global_load_lds(
        (const __attribute__((address_space(1))) unsigned int*)g,
        (__attribute__((address_space(3))) unsigned int*)l, 16, 0, 0);
}

// ------------------- f32 -> bf16 plain cast -------------------
__global__ void k_cast(const float* __restrict__ src, bf16* __restrict__ dst, int n4) {
    int i = blockIdx.x * blockDim.x + threadIdx.x;
    if (i >= n4) return;
    const float4 v = ((const float4*)src)[i];
    bf16x4 hv = {(bf16)v.x, (bf16)v.y, (bf16)v.z, (bf16)v.w};
    ((bf16x4*)dst)[i] = hv;
}

// ------------------- V transpose: [n,h,key,d] -> [n,h,d,key] -------------------
__global__ __launch_bounds__(256) void k_vt(const bf16* __restrict__ v,
                                            bf16* __restrict__ vt) {
    __shared__ bf16 T[256 * 72];   // [key_local][d] padded (+8)
    const int n = blockIdx.z, h = blockIdx.y, kc = blockIdx.x * 256;
    const int tid = threadIdx.x;
    const size_t base1 = ((size_t)n * NH + h) * SL * HD;
    const size_t base2 = ((size_t)n * NH + h) * HD * SL;

#pragma unroll
    for (int ri = 0; ri < 8; ++ri) {
        const int kl = ri * 32 + (tid >> 3), d0 = (tid & 7) * 8;
        const bf16x8 x = *(const bf16x8*)(v + base1 + (size_t)(kc + kl) * HD + d0);
        *(bf16x8*)&T[kl * 72 + d0] = x;
    }
    __syncthreads();

    const int d = tid >> 2, kch = (tid & 3) * 64;
#pragma unroll
    for (int i = 0; i < 8; ++i) {
        bf16x8 y;
#pragma unroll
        for (int e = 0; e < 8; ++e)
            y[e] = T[(kch + i * 8 + e) * 72 + d];
        *(bf16x8*)(vt + base2 + (size_t)d * SL + kc + kch + i * 8) = y;
    }
}

// ------------------- QKV projection GEMM v2: hi-only (1 MFMA/pair) -------------------
__global__ __launch_bounds__(256) void k_qkv_gemm(
    const bf16* __restrict__ xh, const bf16* __restrict__ wh,
    const float* __restrict__ bq, const float* __restrict__ bk,
    const float* __restrict__ bv,
    bf16* __restrict__ qh, bf16* __restrict__ kh, bf16* __restrict__ vh)
{
    __shared__ __attribute__((aligned(16))) bf16 As[128 * 32];
    __shared__ __attribute__((aligned(16))) bf16 Bs[128 * 32];

    const int z  = blockIdx.z;           // 0=q,1=k,2=v
    const int m0 = blockIdx.x * 128;
    const int n0 = blockIdx.y * 128;
    const int tid = threadIdx.x, wave = tid >> 6, lane = tid & 63;
    const int wr = wave >> 1, wc = wave & 1;
    const int fr = lane & 15, fq = lane >> 4;
    const bf16* Wh = wh + (size_t)z * ED * ED;

    const f32x4 z4 = {0.f, 0.f, 0.f, 0.f};
    f32x4 acc[4][4];
#pragma unroll
    for (int i = 0; i < 4; ++i)
#pragma unroll
        for (int j = 0; j < 4; ++j) acc[i][j] = z4;

#pragma unroll 1
    for (int kk = 0; kk < ED; kk += 32) {
#pragma unroll
        for (int r = 0; r < 2; ++r) {
            const int chunk = r * 256 + tid;
            const int row = chunk >> 2, c8 = (chunk & 3) * 8;
            const size_t ax = (size_t)(m0 + row) * ED + kk + c8;
            const size_t bx = (size_t)(n0 + row) * ED + kk + c8;
            const int db = (r * 256 + wave * 64) * 8;   // wave-uniform LDS base
            gl_lds16(xh + ax, &As[db]);
            gl_lds16(Wh + bx, &Bs[db]);
        }
        __syncthreads();
        bf16x8 af[4], bfg[4];
#pragma unroll
        for (int i = 0; i < 4; ++i) {
            const int arow = wr * 64 + i * 16 + fr;
            af[i] = *(const bf16x8*)&As[arow * 32 + fq * 8];
            const int brow = wc * 64 + i * 16 + fr;
            bfg[i] = *(const bf16x8*)&Bs[brow * 32 + fq * 8];
        }
#pragma unroll
        for (int mi = 0; mi < 4; ++mi)
#pragma unroll
            for (int ni = 0; ni < 4; ++ni)
                acc[mi][ni] = MFMA16(af[mi], bfg[ni], acc[mi][ni]);
        __syncthreads();
    }

    const float* bias = (z == 0) ? bq : (z == 1) ? bk : bv;
#pragma unroll
    for (int mi = 0; mi < 4; ++mi) {
#pragma unroll
        for (int ni = 0; ni < 4; ++ni) {
            const int col = n0 + wc * 64 + ni * 16 + fr;
            const int hh = col >> 6, dd = col & 63;
#pragma unroll
            for (int j = 0; j < 4; ++j) {
                const int row = m0 + wr * 64 + mi * 16 + fq * 4 + j;
                float v = acc[mi][ni][j] + bias[col];
                const int nb = row >> 11, li = row & (SL - 1);
                const size_t off = (((size_t)nb * NH + hh) * SL + li) * HD + dd;
                if (z == 0) {
                    qh[off] = (bf16)(v * 0.125f);      // head_dim^-0.5
                } else if (z == 1) {
                    kh[off] = (bf16)v;
                } else {
                    vh[off] = (bf16)v;
                }
            }
        }
    }
}

// ------------------- output projection GEMM v3: hi-only (1 MFMA) -------------------
__global__ __launch_bounds__(256) void k_out_gemm(
    const bf16* __restrict__ ah, const bf16* __restrict__ wh,
    const float* __restrict__ bo, float* __restrict__ out)
{
    __shared__ __attribute__((aligned(16))) bf16 As[128 * 32];
    __shared__ __attribute__((aligned(16))) bf16 Bs[128 * 32];

    const int m0 = blockIdx.x * 128;
    const int n0 = blockIdx.y * 128;
    const int tid = threadIdx.x, wave = tid >> 6, lane = tid & 63;
    const int wr = wave >> 1, wc = wave & 1;
    const int fr = lane & 15, fq = lane >> 4;

    const f32x4 z4 = {0.f, 0.f, 0.f, 0.f};
    f32x4 acc[4][4];
#pragma unroll
    for (int i = 0; i < 4; ++i)
#pragma unroll
        for (int j = 0; j < 4; ++j) acc[i][j] = z4;

#pragma unroll 1
    for (int kk = 0; kk < ED; kk += 32) {
#pragma unroll
        for (int r = 0; r < 2; ++r) {
            const int chunk = r * 256 + tid;
            const int row = chunk >> 2, c8 = (chunk & 3) * 8;
            const size_t ax = (size_t)(m0 + row) * ED + kk + c8;
            const size_t bx = (size_t)(n0 + row) * ED + kk + c8;
            const int db = (r * 256 + wave * 64) * 8;
            gl_lds16(ah + ax, &As[db]);
            gl_lds16(wh + bx, &Bs[db]);
        }
        __syncthreads();
        bf16x8 af[4], bfg[4];
#pragma unroll
        for (int i = 0; i < 4; ++i) {
            const int arow = wr * 64 + i * 16 + fr;
            af[i] = *(const bf16x8*)&As[arow * 32 + fq * 8];
            const int brow = wc * 64 + i * 16 + fr;
            bfg[i] = *(const bf16x8*)&Bs[brow * 32 + fq * 8];
        }
#pragma unroll
        for (int mi = 0; mi < 4; ++mi)
#pragma unroll
            for (int ni = 0; ni < 4; ++ni)
                acc[mi][ni] = MFMA16(af[mi], bfg[ni], acc[mi][ni]);
        __syncthreads();
    }

#pragma unroll
    for (int mi = 0; mi < 4; ++mi)
#pragma unroll
        for (int ni = 0; ni < 4; ++ni) {
            const int col = n0 + wc * 64 + ni * 16 + fr;
#pragma unroll
            for (int j = 0; j < 4; ++j) {
                const int row = m0 + wr * 64 + mi * 16 + fq * 4 + j;
                out[(size_t)row * ED + col] = acc[mi][ni][j] + bo[col];
            }
        }
}

// ------------------- flash attention v12: DMA-staged K/V + fused mlg epilogue -------------------
__global__ __launch_bounds__(256) void k_flash(
    const bf16* __restrict__ qh, const bf16* __restrict__ kh,
    const bf16* __restrict__ vt,
    const float* __restrict__ bias, const int* __restrict__ mask,
    bf16* __restrict__ ch, float* __restrict__ mlg)
{
    __shared__ __attribute__((aligned(16))) bf16 Ks[2][64 * 64];  // [key][d] swz, dbuf
    __shared__ __attribute__((aligned(16))) bf16 Vs[2][64 * 64];  // [d][key] swz, dbuf
    __shared__ __attribute__((aligned(16))) bf16 Ws[4][16 * 64];  // per-wave P, swz

    const int bid = blockIdx.x;
    const int xcd = bid & 7, local = bid >> 3;
    const int h = xcd * 2 + (local >> 6);
    const int rem = local & 63;
    const int qt = rem >> 2, n = rem & 3;

    const int tid = threadIdx.x, wave = tid >> 6, lane = tid & 63;
    const int fr = lane & 15, fq = lane >> 4;
    const int frx = fr & 7;
    const int q0 = qt * 128;
    const int qw = q0 + wave * 32;                  // wave's 32-row base
    const size_t hoff = ((size_t)n * NH + h) * SL * HD;  // same value for vT base
    const f32x4 z4 = {0.f, 0.f, 0.f, 0.f};

    bf16x8 qf0[2], qf1[2];
#pragma unroll
    for (int m = 0; m < 2; ++m) {
        const size_t qb = hoff + (size_t)(qw + m * 16 + fr) * HD + fq * 8;
        qf0[m] = *(const bf16x8*)(qh + qb);
        qf1[m] = *(const bf16x8*)(qh + qb + 32);
    }

    f32x4 o[2][4];
#pragma unroll
    for (int m = 0; m < 2; ++m)
#pragma unroll
        for (int f = 0; f < 4; ++f) o[m][f] = z4;
    float mj[2][4], sj[2][4];   // sj: LANE-LOCAL partial sums
#pragma unroll
    for (int m = 0; m < 2; ++m)
#pragma unroll
        for (int j = 0; j < 4; ++j) { mj[m][j] = -3e38f; sj[m][j] = 0.f; }

    const int* mkb = mask + n * SL;
    const float* bh = bias + (size_t)h * SL * SL;

    auto stageK = [&](int kt2, int b) {
#pragma unroll
        for (int i = 0; i < 2; ++i) {
            const int li = i * 256 + tid;
            const int r = li >> 3, s = li & 7;
            gl_lds16(kh + hoff + (size_t)(kt2 * 64 + r) * HD + (s ^ (r & 7)) * 8,
                     &Ks[b][(i * 256 + wave * 64) * 8]);
        }
    };
    auto stageV = [&](int kt2, int b) {
#pragma unroll
        for (int i = 0; i < 2; ++i) {
            const int li = i * 256 + tid;
            const int r = li >> 3, s = li & 7;      // r = d row
            gl_lds16(vt + hoff + (size_t)r * SL + kt2 * 64 + (s ^ (r & 7)) * 8,
                     &Vs[b][(i * 256 + wave * 64) * 8]);
        }
    };

    // ---- prologue ----
    stageK(0, 0);
    stageV(0, 0);
    __syncthreads();   // drains K(0)+V(0) DMA

#pragma unroll 1
    for (int kt = 0; kt < 32; ++kt) {
        const int cur = kt & 1, nxt = cur ^ 1;
        const int kp1 = (kt < 31) ? kt + 1 : 31;

        // 0. mask bits for THIS tile
        const int mw0 = mkb[kt * 64 + fr];
        const int mw1 = mkb[kt * 64 + 16 + fr];
        const int mw2 = mkb[kt * 64 + 32 + fr];
        const int mw3 = mkb[kt * 64 + 48 + fr];

        // 1. issue next-tile K/V DMA
        stageK(kp1, nxt);
        stageV(kp1, nxt);
        const int mbits = (mw0 != 0 ? 1 : 0) | (mw1 != 0 ? 2 : 0)
                        | (mw2 != 0 ? 4 : 0) | (mw3 != 0 ? 8 : 0);

        // ---- compute: two independent 16-row chains ----
#pragma unroll
        for (int m = 0; m < 2; ++m) {
            float bfr[4][4];
#pragma unroll
            for (int nf = 0; nf < 4; ++nf)
#pragma unroll
                for (int j = 0; j < 4; ++j)
                    bfr[nf][j] = bh[(size_t)(qw + m * 16 + fq * 4 + j) * SL
                                    + kt * 64 + nf * 16 + fr];

            f32x4 sf[4];
            __builtin_amdgcn_s_setprio(1);
#pragma unroll
            for (int nf = 0; nf < 4; ++nf) {
                const bf16* kp = &Ks[cur][(nf * 16 + fr) * 64];
                const bf16x8 b0 = *(const bf16x8*)&kp[(fq ^ frx) * 8];
                const bf16x8 b1 = *(const bf16x8*)&kp[((fq + 4) ^ frx) * 8];
                f32x4 a = z4;
                a = MFMA16(qf0[m], b0, a);
                a = MFMA16(qf1[m], b1, a);
                sf[nf] = a;
            }
            __builtin_amdgcn_s_setprio(0);

            // bias + mask
#pragma unroll
            for (int nf = 0; nf < 4; ++nf) {
                const bool mk = (mbits >> nf) & 1;
#pragma unroll
                for (int j = 0; j < 4; ++j) {
                    float s = sf[nf][j] + bfr[nf][j];
                    sf[nf][j] = mk ? -1e30f : s;
                }
            }

            // defer-max online softmax (common path: no cross-lane ops)
            float tmax[4];
#pragma unroll
            for (int j = 0; j < 4; ++j)
                tmax[j] = fmaxf(fmaxf(sf[0][j], sf[1][j]), fmaxf(sf[2][j], sf[3][j]));
            bool need = false;
#pragma unroll
            for (int j = 0; j < 4; ++j)
                need = need || (tmax[j] > mj[m][j] + 8.0f);
            if (__any(need)) {
#pragma unroll
                for (int d = 1; d < 16; d <<= 1)
#pragma unroll
                    for (int j = 0; j < 4; ++j)
                        tmax[j] = fmaxf(tmax[j], __shfl_xor(tmax[j], d));
#pragma unroll
                for (int j = 0; j < 4; ++j) {
                    const float mn = fmaxf(mj[m][j], tmax[j]);
                    const float scale = __expf(mj[m][j] - mn);
                    mj[m][j] = mn;
                    sj[m][j] *= scale;
#pragma unroll
                    for (int f = 0; f < 4; ++f) o[m][f][j] *= scale;
                }
            }
#pragma unroll
            for (int nf = 0; nf < 4; ++nf)
#pragma unroll
                for (int j = 0; j < 4; ++j) {
                    const float w = __expf(sf[nf][j] - mj[m][j]);
                    sf[nf][j] = w;
                    sj[m][j] += w;
                }

            // P -> per-wave swizzled LDS tile (wave-local; reused across m)
#pragma unroll
            for (int nf = 0; nf < 4; ++nf)
#pragma unroll
                for (int j = 0; j < 4; ++j) {
                    const int row = fq * 4 + j, col = nf * 16 + fr;
                    Ws[wave][row * 64 + (((col >> 3) ^ (row & 7)) << 3) + (fr & 7)] =
                        (bf16)sf[nf][j];
                }
            const bf16* wp = &Ws[wave][fr * 64];
            const bf16x8 wa0 = *(const bf16x8*)&wp[(fq ^ frx) * 8];
            const bf16x8 wa1 = *(const bf16x8*)&wp[((fq + 4) ^ frx) * 8];
            __builtin_amdgcn_s_setprio(1);
#pragma unroll
            for (int f = 0; f < 4; ++f) {
                const bf16* vp = &Vs[cur][(f * 16 + fr) * 64];
                const bf16x8 vb0 = *(const bf16x8*)&vp[(fq ^ frx) * 8];
                const bf16x8 vb1 = *(const bf16x8*)&vp[((fq + 4) ^ frx) * 8];
                o[m][f] = MFMA16(wa0, vb0, o[m][f]);
                o[m][f] = MFMA16(wa1, vb1, o[m][f]);
            }
            __builtin_amdgcn_s_setprio(0);
        }

        __syncthreads();   // drains K/V(kt+1) DMA; fences buffer swap
    }

    // epilogue: reduce lane-local sj across the 16-lane row group (once)
#pragma unroll
    for (int m = 0; m < 2; ++m)
#pragma unroll
        for (int d = 1; d < 16; d <<= 1)
#pragma unroll
            for (int j = 0; j < 4; ++j)
                sj[m][j] += __shfl_xor(sj[m][j], d);

    // context (hi only) + fused mlg = m + ln(16 s)
#pragma unroll
    for (int m = 0; m < 2; ++m) {
#pragma unroll
        for (int j = 0; j < 4; ++j) {
            const float inv = 1.0f / sj[m][j];
            const int row = n * SL + qw + m * 16 + fq * 4 + j;
#pragma unroll
            for (int f = 0; f < 4; ++f) {
                const float v = o[m][f][j] * inv;
                const size_t off = (size_t)row * ED + h * HD + f * 16 + fr;
                ch[off] = (bf16)v;
            }
        }
        if (fr == 0) {
#pragma unroll
            for (int j = 0; j < 4; ++j) {
                const int r = qw + m * 16 + fq * 4 + j;
                mlg[((size_t)n * NH + h) * SL + r] =
                    mj[m][j] + __logf(16.0f * sj[m][j]);
            }
        }
    }
}

// ------------------- head-averaged weights v7.1 (measured-best) -------------------
__global__ __launch_bounds__(256) void k_avg(
    const bf16* __restrict__ qh, const bf16* __restrict__ kh,
    const float* __restrict__ bias, const int* __restrict__ mask,
    const float* __restrict__ mlg, float* __restrict__ avg)
{
    __shared__ __attribute__((aligned(16))) bf16 Ks2[2][64 * 64];   // 16 KB
    __shared__ __attribute__((aligned(16))) float Bs2[2][64 * 64];  // 32 KB

    const int qt = blockIdx.x, kt = blockIdx.y;
    const int tid = threadIdx.x, wave = tid >> 6, lane = tid & 63;
    const int fr = lane & 15, fq = lane >> 4;
    const int frx = fr & 7;
    const int q0 = qt * 64, k0 = kt * 64;
    const int qr = q0 + wave * 16;
    const f32x4 z4 = {0.f, 0.f, 0.f, 0.f};

    f32x4 acc[4][4];
#pragma unroll
    for (int nn = 0; nn < 4; ++nn)
#pragma unroll
        for (int nf = 0; nf < 4; ++nf) acc[nn][nf] = z4;

    int mkbits = 0;
#pragma unroll
    for (int nn = 0; nn < 4; ++nn)
#pragma unroll
        for (int nf = 0; nf < 4; ++nf)
            mkbits |= (mask[nn * SL + k0 + nf * 16 + fr] != 0 ? 1 : 0) << (nn * 4 + nf);

    auto stageK = [&](int hh, int nn2, int b) {
        const bf16* kb = kh + (((size_t)nn2 * NH + hh) * SL + k0) * HD;
#pragma unroll
        for (int i = 0; i < 2; ++i) {
            const int li = i * 256 + tid;
            const int r = li >> 3, s = li & 7;
            gl_lds16(kb + (size_t)r * HD + (s ^ (r & 7)) * 8,
                     &Ks2[b][(i * 256 + wave * 64) * 8]);
        }
    };
    auto stageB = [&](int hh, int b) {   // 64x64 f32 bias tile, 4 chunks
        const float* bb = bias + (size_t)hh * SL * SL + (size_t)q0 * SL + k0;
#pragma unroll
        for (int i = 0; i < 4; ++i) {
            const int li = i * 256 + tid;
            const int r = li >> 4, c = li & 15;
            gl_lds16(bb + (size_t)r * SL + c * 4,
                     &Bs2[b][(i * 256 + wave * 64) * 4]);
        }
    };
    auto loadQ = [&](int hh, int nn2, bf16x8& a0, bf16x8& a1) {
        const bf16* qb = qh + ((((size_t)nn2 * NH + hh) * SL + qr + fr) * HD) + fq * 8;
        a0 = *(const bf16x8*)qb;
        a1 = *(const bf16x8*)(qb + 32);
    };
    auto loadMlg = [&](int hh, int nn2) -> f32x4 {
        return *(const f32x4*)(mlg + ((size_t)nn2 * NH + hh) * SL + qr + fq * 4);
    };

    // prologue: K(0,0), bias(h=0); Q(0,0)+mlg(0,0) -> regs
    stageK(0, 0, 0);
    stageB(0, 0);
    bf16x8 qcA, qcB;
    loadQ(0, 0, qcA, qcB);
    f32x4 mlgc = loadMlg(0, 0);
    __syncthreads();

#pragma unroll 1
    for (int h = 0; h < NH; ++h) {
        const int hb = h & 1;
#pragma unroll
        for (int nn = 0; nn < 4; ++nn) {
            const int ih = h * 4 + nn;           // unrolled: parity compile-time
            const int buf = ih & 1;

            // prefetch next step: K -> LDS, Q+mlg -> regs; bias(h+1) at nn==0
            bf16x8 qnA, qnB;
            f32x4 mlgn = mlgc;
            if (ih < 63) {
                const int jh = (ih + 1) >> 2, jnn = (ih + 1) & 3;
                stageK(jh, jnn, buf ^ 1);
                loadQ(jh, jnn, qnA, qnB);
                mlgn = loadMlg(jh, jnn);
            } else {
                qnA = qcA; qnB = qcB;
            }
            if (nn == 0 && h < NH - 1) stageB(h + 1, hb ^ 1);

            // compute on current (qcA/qcB, Ks2[buf], Bs2[hb], mlgc)
#pragma unroll
            for (int nf = 0; nf < 4; ++nf) {
                const bf16* kp = &Ks2[buf][(nf * 16 + fr) * 64];
                const bf16x8 b0 = *(const bf16x8*)&kp[(fq ^ frx) * 8];
                const bf16x8 b1 = *(const bf16x8*)&kp[((fq + 4) ^ frx) * 8];
                f32x4 a = z4;
                a = MFMA16(qcA, b0, a);
                a = MFMA16(qcB, b1, a);
                const bool mk = (mkbits >> (nn * 4 + nf)) & 1;
#pragma unroll
                for (int j = 0; j < 4; ++j) {
                    const float w = mk ? 0.f
                        : __expf(a[j] + Bs2[hb][(wave * 16 + fq * 4 + j) * 64
                                                + nf * 16 + fr]
                                 - mlgc[j]);
                    acc[nn][nf][j] += w;
                }
            }
            __syncthreads();    // drains next K (+bias) DMA; fences swap
            qcA = qnA; qcB = qnB; mlgc = mlgn;
        }
    }

#pragma unroll
    for (int nn = 0; nn < 4; ++nn)
#pragma unroll
        for (int j = 0; j < 4; ++j) {
            const size_t rowoff = ((size_t)nn * SL + qr + fq * 4 + j) * SL;
#pragma unroll
            for (int nf = 0; nf < 4; ++nf)
                avg[rowoff + k0 + nf * 16 + fr] = acc[nn][nf][j];
        }
}

// ------------------- launcher -------------------
extern "C" void kernel_launch(void* const* d_in, const int* in_sizes, int n_in,
                              void* d_out, int out_size, void* d_ws, size_t ws_size,
                              hipStream_t stream)
{
    (void)in_sizes; (void)n_in; (void)out_size; (void)ws_size;
    const float* query = (const float*)d_in[0];
    const float* bias  = (const float*)d_in[1];
    const int* mask = (const int*)d_in[2];
    const float* Wq = (const float*)d_in[3];
    const float* bq = (const float*)d_in[4];
    const float* Wk = (const float*)d_in[5];
    const float* bk = (const float*)d_in[6];
    const float* Wv = (const float*)d_in[7];
    const float* bv = (const float*)d_in[8];
    const float* Wo = (const float*)d_in[9];
    const float* bo = (const float*)d_in[10];
    float* out0 = (float*)d_out;                      // [N,L,E]
    float* out1 = out0 + (size_t)MR * ED;             // [N,L,L]

    char* p = (char*)d_ws;
    auto carve = [&](size_t bytes) {
        char* r = p;
        p += (bytes + 255) & ~(size_t)255;
        return r;
    };
    const size_t QKVB = (size_t)NB * NH * SL * HD * 2;   // 16.78 MB
    bf16* xh = (bf16*)carve((size_t)MR * ED * 2);
    bf16* wall = (bf16*)carve((size_t)4 * ED * ED * 2);  // Wq,Wk,Wv,Wo hi
    bf16* qh = (bf16*)carve(QKVB);
    bf16* kh = (bf16*)carve(QKVB);
    bf16* vh = (bf16*)carve(QKVB);
    bf16* vtb = (bf16*)carve(QKVB);
    float* mlg  = (float*)carve((size_t)NB * NH * SL * 4);
    bf16* ch = (bf16*)carve((size_t)MR * ED * 2);

    // 1. casts (separate launches; round-22-proven pattern)
    {
        const int n4 = MR * ED / 4;
        k_cast<<<(n4 + 255) / 256, 256, 0, stream>>>(query, xh, n4);
        const int w4 = ED * ED / 4;
        const float* Ws4[4] = {Wq, Wk, Wv, Wo};
        for (int i = 0; i < 4; ++i)
            k_cast<<<(w4 + 255) / 256, 256, 0, stream>>>(
                Ws4[i], wall + (size_t)i * ED * ED, w4);
    }
    // 2. QKV projections (hi-only)
    k_qkv_gemm<<<dim3(MR / 128, ED / 128, 3), 256, 0, stream>>>(
        xh, wall, bq, bk, bv, qh, kh, vh);
    // 2b. V transpose -> [n,h,d,key]
    k_vt<<<dim3(SL / 256, NH, NB), 256, 0, stream>>>(vh, vtb);
    // 3. flash attention + context + fused mlg (QBLK=128 -> 1024 blocks)
    k_flash<<<dim3(1024), 256, 0, stream>>>(
        qh, kh, vtb, bias, mask, ch, mlg);
    // 4. head-averaged attention weights (64x64 tiles)
    k_avg<<<dim3(SL / 64, SL / 64), 256, 0, stream>>>(
        qh, kh, bias, mask, mlg, out1);
    // 5. output projection (hi-only)
    k_out_gemm<<<dim3(MR / 128, ED / 128), 256, 0, stream>>>(
        ch, wall + (size_t)3 * ED * ED, bo, out0);
}